// Round 1
// baseline (201.874 us; speedup 1.0000x reference)
//
#include <hip/hip_runtime.h>
#include <hip/hip_bf16.h>
#include <stdint.h>

typedef __attribute__((ext_vector_type(8))) __bf16 bf16x8;
typedef __attribute__((ext_vector_type(4))) float f32x4;

#define C192 192
#define NSP 65536
#define SL 512
#define CHUNK 128
#define NCHUNK 4
#define EPS_N 1e-12f

__device__ __forceinline__ uint32_t f2bf1(float a){
  uint32_t u = __float_as_uint(a);
  return (u + 0x7fffu + ((u >> 16) & 1u)) >> 16;
}
__device__ __forceinline__ uint32_t f2bf2(float lo, float hi){
  return f2bf1(lo) | (f2bf1(hi) << 16);
}

// ---------------- K1: Gram partials + row-sums (ones-row trick) + xT bf16 copy
// grid 256: b = bid>>7, slice = bid&127 handles x[b][:, slice*512 .. +512)
__global__ __launch_bounds__(256) void k_gram(const float* __restrict__ x,
                                              float* __restrict__ gpart,
                                              ushort* __restrict__ xT){
  __shared__ ushort xs[208 * CHUNK];   // [row][col] bf16, XOR-swizzled rows
  char* lb = (char*)xs;
  const int tid = threadIdx.x;
  const int lane = tid & 63, wid = tid >> 6;
  const int l15 = lane & 15, hi = lane >> 4;
  const int bid = blockIdx.x;
  const int b = bid >> 7, slice = bid & 127;
  const int j0 = slice * SL;

  // constant rows 192..207: row 192 = 1.0 (bf16 0x3F80), rows 193..207 = 0
  for (int i = tid; i < 16 * CHUNK; i += 256)
    xs[192 * CHUNK + i] = (i < CHUNK) ? (ushort)0x3F80 : (ushort)0;

  f32x4 acc[3][13];
  #pragma unroll
  for (int i = 0; i < 3; i++)
    #pragma unroll
    for (int j = 0; j < 13; j++)
      acc[i][j] = (f32x4){0.f, 0.f, 0.f, 0.f};

  const float* xb = x + ((size_t)b * C192) * NSP;

  for (int ch = 0; ch < NCHUNK; ch++){
    __syncthreads();
    // stage 192x128 fp32 -> bf16 LDS (swizzled)
    #pragma unroll 4
    for (int i = 0; i < 24; i++){
      int idx = i * 256 + tid;
      int r = idx >> 5, c4 = idx & 31;
      const float4 v = *(const float4*)(xb + (size_t)r * NSP + j0 + ch * CHUNK + c4 * 4);
      uint2 u; u.x = f2bf2(v.x, v.y); u.y = f2bf2(v.z, v.w);
      int byte = r * (CHUNK * 2) + c4 * 8; byte ^= (r & 7) << 4;
      *(uint2*)(lb + byte) = u;
    }
    __syncthreads();
    // MFMA: 12 row-tiles x 13 col-tiles (ct=12 = ones-row -> row sums)
    #pragma unroll
    for (int ks = 0; ks < 4; ks++){
      bf16x8 a[3];
      #pragma unroll
      for (int i = 0; i < 3; i++){
        int row = (wid * 3 + i) * 16 + l15;
        int byte = row * (CHUNK * 2) + ks * 64 + hi * 16; byte ^= (l15 & 7) << 4;
        a[i] = *(const bf16x8*)(lb + byte);
      }
      #pragma unroll
      for (int ct = 0; ct < 13; ct++){
        int row = ct * 16 + l15;
        int byte = row * (CHUNK * 2) + ks * 64 + hi * 16; byte ^= (l15 & 7) << 4;
        bf16x8 bf = *(const bf16x8*)(lb + byte);
        #pragma unroll
        for (int i = 0; i < 3; i++)
          acc[i][ct] = __builtin_amdgcn_mfma_f32_16x16x32_bf16(a[i], bf, acc[i][ct], 0, 0, 0);
      }
    }
    // xT bf16 copy: [sp][chan] from staged LDS
    {
      int sp = tid & 127, halfc = (tid >> 7) * 96;
      ushort* dst = xT + ((size_t)b * NSP + j0 + ch * CHUNK + sp) * C192;
      #pragma unroll
      for (int i = 0; i < 12; i++){
        uint4 w;
        uint32_t t[4];
        #pragma unroll
        for (int jj = 0; jj < 4; jj++){
          int ch0 = halfc + i * 8 + jj * 2;
          int by0 = ch0 * (CHUNK * 2) + sp * 2; by0 ^= (ch0 & 7) << 4;
          int ch1 = ch0 + 1;
          int by1 = ch1 * (CHUNK * 2) + sp * 2; by1 ^= (ch1 & 7) << 4;
          t[jj] = (uint32_t)(*(const ushort*)(lb + by0)) |
                  ((uint32_t)(*(const ushort*)(lb + by1)) << 16);
        }
        w.x = t[0]; w.y = t[1]; w.z = t[2]; w.w = t[3];
        *(uint4*)(dst + halfc + i * 8) = w;
      }
    }
  }
  // store partials [bid][192][193]  (col 192 = partial row-sum s)
  float* gp = gpart + (size_t)bid * (C192 * 193);
  #pragma unroll
  for (int i = 0; i < 3; i++){
    int row0 = (wid * 3 + i) * 16 + hi * 4;
    #pragma unroll
    for (int ct = 0; ct < 13; ct++){
      if (ct < 12){
        int col = ct * 16 + l15;
        #pragma unroll
        for (int r = 0; r < 4; r++) gp[(row0 + r) * 193 + col] = acc[i][ct][r];
      } else if (l15 == 0){
        #pragma unroll
        for (int r = 0; r < 4; r++) gp[(row0 + r) * 193 + 192] = acc[i][ct][r];
      }
    }
  }
}

// ---------------- K2: reduce partials -> G_aug [2][192][193]; plus WkT transpose
__global__ __launch_bounds__(256) void k_reduce(const float* __restrict__ gpart,
                                                float* __restrict__ gaug,
                                                const float* __restrict__ qkv_w,
                                                float* __restrict__ wkT){
  int blk = blockIdx.x, tid = threadIdx.x;
  if (blk < 384){
    int b = blk / 192, r = blk % 192;
    if (tid < 193){
      float s = 0.f;
      const float* p = gpart + (size_t)b * 128 * (C192 * 193) + r * 193 + tid;
      #pragma unroll 8
      for (int sl = 0; sl < 128; sl++) s += p[(size_t)sl * (C192 * 193)];
      gaug[(b * C192 + r) * 193 + tid] = s;
    }
  } else {
    int idx = (blk - 384) * 256 + tid;
    if (idx < 36864){
      int d = idx / 192, e = idx % 192;
      wkT[e * 192 + d] = qkv_w[(192 + d) * 192 + e];
    }
  }
}

// ---------------- T1: P_aug = Wq*G_aug, R_aug = Wk*G_aug; plus q/k norms
__global__ __launch_bounds__(256) void k_pr(const float* __restrict__ gaug,
                                            const float* __restrict__ qkv_w,
                                            const float* __restrict__ qkv_b,
                                            float* __restrict__ pr,
                                            float* __restrict__ norms){
  __shared__ float red[4];
  __shared__ float uSh;
  int blk = blockIdx.x, tid = threadIdx.x;
  int b = blk / 384, which = (blk / 192) % 2, c = blk % 192;
  const float* wrow = qkv_w + (which * 192 + c) * 192;
  float acc = 0.f;
  if (tid < 193){
    const float* g = gaug + (size_t)b * C192 * 193 + tid;
    #pragma unroll 4
    for (int e = 0; e < 192; e++) acc += wrow[e] * g[(size_t)e * 193];
    pr[(((size_t)b * 2 + which) * 192 + c) * 193 + tid] = acc;
  }
  if (tid == 192) uSh = acc;
  float v = (tid < 192) ? acc * wrow[tid] : 0.f;
  for (int o = 32; o > 0; o >>= 1) v += __shfl_down(v, o, 64);
  if ((tid & 63) == 0) red[tid >> 6] = v;
  __syncthreads();
  if (tid == 0){
    float s = red[0] + red[1] + red[2] + red[3];
    float bias = qkv_b[which * 192 + c];
    float n2 = s + 2.f * bias * uSh + 65536.f * bias * bias;
    norms[(b * 2 + which) * 192 + c] = fmaxf(sqrtf(fmaxf(n2, 0.f)), EPS_N);
  }
}

// ---------------- T3: S row -> scaled softmax -> attn [2][192][192]
__global__ __launch_bounds__(256) void k_attn(const float* __restrict__ pr,
                                              const float* __restrict__ wkT,
                                              const float* __restrict__ norms,
                                              const float* __restrict__ qkv_b,
                                              const float* __restrict__ temperature,
                                              float* __restrict__ attn){
  __shared__ float Pc[193];
  __shared__ float red[4];
  __shared__ float bcast;
  int blk = blockIdx.x, tid = threadIdx.x;
  int b = blk / 192, c = blk % 192;
  if (tid < 193) Pc[tid] = pr[(((size_t)b * 2 + 0) * 192 + c) * 193 + tid];
  __syncthreads();
  int d = tid;
  float logit = -1e30f, p = 0.f;
  if (d < 192){
    float sS = 0.f;
    #pragma unroll 4
    for (int e = 0; e < 192; e++) sS += Pc[e] * wkT[e * 192 + d];
    float bq = qkv_b[c], bk = qkv_b[192 + d];
    float w2 = pr[(((size_t)b * 2 + 1) * 192 + d) * 193 + 192];
    float Sv = sS + Pc[192] * bk + bq * w2 + 65536.f * bq * bk;
    float nq = norms[(b * 2 + 0) * 192 + c];
    float nk = norms[(b * 2 + 1) * 192 + d];
    logit = temperature[0] * Sv / (nq * nk);
  }
  float m = logit;
  for (int o = 32; o > 0; o >>= 1) m = fmaxf(m, __shfl_down(m, o, 64));
  if ((tid & 63) == 0) red[tid >> 6] = m;
  __syncthreads();
  if (tid == 0) bcast = fmaxf(fmaxf(red[0], red[1]), fmaxf(red[2], red[3]));
  __syncthreads();
  m = bcast;
  p = (d < 192) ? __expf(logit - m) : 0.f;
  float s = p;
  for (int o = 32; o > 0; o >>= 1) s += __shfl_down(s, o, 64);
  __syncthreads();
  if ((tid & 63) == 0) red[tid >> 6] = s;
  __syncthreads();
  if (tid == 0) bcast = red[0] + red[1] + red[2] + red[3];
  __syncthreads();
  if (d < 192) attn[((size_t)b * 192 + c) * 192 + d] = p / bcast;
}

// ---------------- T4: U_aug = attn @ [Wv | bv]   [2][192][193]
__global__ __launch_bounds__(256) void k_u(const float* __restrict__ attn,
                                           const float* __restrict__ qkv_w,
                                           const float* __restrict__ qkv_b,
                                           float* __restrict__ uaug){
  __shared__ float arow[192];
  int blk = blockIdx.x, tid = threadIdx.x;
  int b = blk / 192, c = blk % 192;
  if (tid < 192) arow[tid] = attn[((size_t)b * 192 + c) * 192 + tid];
  __syncthreads();
  int e = tid;
  if (e <= 192){
    float acc = 0.f;
    if (e < 192){
      #pragma unroll 4
      for (int d = 0; d < 192; d++) acc += arow[d] * qkv_w[(384 + d) * 192 + e];
    } else {
      #pragma unroll 4
      for (int d = 0; d < 192; d++) acc += arow[d] * qkv_b[384 + d];
    }
    uaug[((size_t)b * 192 + c) * 193 + e] = acc;
  }
}

// ---------------- T5: F = proj_w @ U (bf16), g = proj_w@h + proj_b
__global__ __launch_bounds__(256) void k_f(const float* __restrict__ uaug,
                                           const float* __restrict__ proj_w,
                                           const float* __restrict__ proj_b,
                                           ushort* __restrict__ fb,
                                           float* __restrict__ gvec){
  __shared__ float pw[192];
  int blk = blockIdx.x, tid = threadIdx.x;
  int b = blk / 192, f = blk % 192;
  if (tid < 192) pw[tid] = proj_w[f * 192 + tid];
  __syncthreads();
  int e = tid;
  if (e <= 192){
    float acc = 0.f;
    const float* u = uaug + (size_t)b * 192 * 193 + e;
    #pragma unroll 4
    for (int c2 = 0; c2 < 192; c2++) acc += pw[c2] * u[(size_t)c2 * 193];
    if (e < 192) fb[((size_t)b * 192 + f) * 192 + e] = (ushort)f2bf1(acc);
    else gvec[b * 192 + f] = acc + proj_b[f];
  }
}

// ---------------- K3: out = F @ x + g 1^T   (B-frags straight from xT, no LDS)
__global__ __launch_bounds__(256) void k_out(const ushort* __restrict__ xT,
                                             const ushort* __restrict__ fb,
                                             const float* __restrict__ gvec,
                                             float* __restrict__ out){
  const int tid = threadIdx.x;
  const int lane = tid & 63, wid = tid >> 6;
  const int l15 = lane & 15, hi = lane >> 4;
  const int bid = blockIdx.x;
  const int b = bid >> 9, cb = bid & 511;
  const int j0 = cb * 128;

  bf16x8 ff[3][6];
  float gfr[3][4];
  #pragma unroll
  for (int i = 0; i < 3; i++){
    int row = (wid * 3 + i) * 16 + l15;
    const ushort* fr = fb + ((size_t)b * 192 + row) * 192;
    #pragma unroll
    for (int ks = 0; ks < 6; ks++) ff[i][ks] = *(const bf16x8*)(fr + ks * 32 + hi * 8);
    #pragma unroll
    for (int r = 0; r < 4; r++)
      gfr[i][r] = gvec[b * 192 + (wid * 3 + i) * 16 + hi * 4 + r];
  }
  f32x4 acc[3][8];
  #pragma unroll
  for (int i = 0; i < 3; i++)
    #pragma unroll
    for (int j = 0; j < 8; j++)
      acc[i][j] = (f32x4){0.f, 0.f, 0.f, 0.f};

  const ushort* xb = xT + ((size_t)b * NSP + j0) * C192;
  #pragma unroll
  for (int ct = 0; ct < 8; ct++){
    #pragma unroll
    for (int ks = 0; ks < 6; ks++){
      bf16x8 bf = *(const bf16x8*)(xb + (size_t)(ct * 16 + l15) * C192 + ks * 32 + hi * 8);
      #pragma unroll
      for (int i = 0; i < 3; i++)
        acc[i][ct] = __builtin_amdgcn_mfma_f32_16x16x32_bf16(ff[i][ks], bf, acc[i][ct], 0, 0, 0);
    }
  }
  #pragma unroll
  for (int i = 0; i < 3; i++){
    int row0 = (wid * 3 + i) * 16 + hi * 4;
    #pragma unroll
    for (int ct = 0; ct < 8; ct++){
      int sp = j0 + ct * 16 + l15;
      float* ob = out + ((size_t)b * 192 + row0) * NSP + sp;
      #pragma unroll
      for (int r = 0; r < 4; r++) ob[(size_t)r * NSP] = acc[i][ct][r] + gfr[i][r];
    }
  }
}

extern "C" void kernel_launch(void* const* d_in, const int* in_sizes, int n_in,
                              void* d_out, int out_size, void* d_ws, size_t ws_size,
                              hipStream_t stream){
  const float* x           = (const float*)d_in[0];
  const float* temperature = (const float*)d_in[1];
  const float* qkv_w       = (const float*)d_in[2];
  const float* qkv_b       = (const float*)d_in[3];
  const float* proj_w      = (const float*)d_in[4];
  const float* proj_b      = (const float*)d_in[5];
  float* out = (float*)d_out;
  char* ws = (char*)d_ws;

  float*  gpart = (float*) (ws);                 // 256*192*193*4 = 37,945,344
  ushort* xT    = (ushort*)(ws + 37945344);      // 2*65536*192*2 = 50,331,648
  float*  gaug  = (float*) (ws + 88276992);      // 296,448
  float*  pr    = (float*) (ws + 88573440);      // 592,896
  float*  wkT   = (float*) (ws + 89166336);      // 147,456
  float*  norms = (float*) (ws + 89313792);      // 3,072
  float*  attn  = (float*) (ws + 89316864);      // 294,912
  float*  uaug  = (float*) (ws + 89611776);      // 296,448
  ushort* fb    = (ushort*)(ws + 89908224);      // 147,456
  float*  gvec  = (float*) (ws + 90055680);      // 1,536

  hipLaunchKernelGGL(k_gram,   dim3(256),  dim3(256), 0, stream, x, gpart, xT);
  hipLaunchKernelGGL(k_reduce, dim3(528),  dim3(256), 0, stream, gpart, gaug, qkv_w, wkT);
  hipLaunchKernelGGL(k_pr,     dim3(768),  dim3(256), 0, stream, gaug, qkv_w, qkv_b, pr, norms);
  hipLaunchKernelGGL(k_attn,   dim3(384),  dim3(256), 0, stream, pr, wkT, norms, qkv_b, temperature, attn);
  hipLaunchKernelGGL(k_u,      dim3(384),  dim3(256), 0, stream, attn, qkv_w, qkv_b, uaug);
  hipLaunchKernelGGL(k_f,      dim3(384),  dim3(256), 0, stream, uaug, proj_w, proj_b, fb, gvec);
  hipLaunchKernelGGL(k_out,    dim3(1024), dim3(256), 0, stream, xT, fb, gvec, out);
}

// Round 3
// 181.624 us; speedup vs baseline: 1.1115x; 1.1115x over previous
//
#include <hip/hip_runtime.h>
#include <hip/hip_bf16.h>
#include <stdint.h>

typedef __attribute__((ext_vector_type(8))) __bf16 bf16x8;
typedef __attribute__((ext_vector_type(4))) float f32x4;
typedef __attribute__((ext_vector_type(4))) uint u32x4;

#define C192 192
#define NSP 65536
#define EPS_N 1e-12f

// per-slice compact partial layout (bf16): 78 full 16x16 tiles + 12 ones-col tiles(16)
#define SLICE_ELEMS 20224
#define ONES_OFF_E 19968   // 78*256

__device__ __forceinline__ uint32_t f2bf1(float a){
  uint32_t u = __float_as_uint(a);
  return (u + 0x7fffu + ((u >> 16) & 1u)) >> 16;
}
__device__ __forceinline__ uint32_t f2bf2(float lo, float hi){
  return f2bf1(lo) | (f2bf1(hi) << 16);
}
__device__ __forceinline__ float bf2f(ushort u){
  return __uint_as_float(((uint32_t)u) << 16);
}

// ---------------- K1: Gram upper-tri partials (bf16 compact) + row-sums + xb16 copy
// grid 512: b = bid>>8, slice = bid&255 handles x[b][:, slice*256 .. +256)
// 6 waves; wave w owns row-tiles {w, 11-w}: 15 tiles of (i,j), j>=i, incl ones-col j=12
__global__ __launch_bounds__(384, 3) void k_gram(const float* __restrict__ x,
                                                 ushort* __restrict__ gpart,
                                                 ushort* __restrict__ xb16){
  __shared__ ushort xs[208 * 128];   // [row][col] bf16, XOR-swizzled rows
  char* lb = (char*)xs;
  const int tid = threadIdx.x;
  const int lane = tid & 63, wid = tid >> 6;
  const int l15 = lane & 15, hi = lane >> 4;
  const int b = blockIdx.x >> 8, slice = blockIdx.x & 255;
  const int j0 = slice * 256;

  // constant rows 192..207: row 192 = 1.0 (bf16 0x3F80), rows 193..207 = 0
  for (int i = tid; i < 16 * 128; i += 384)
    xs[192 * 128 + i] = (i < 128) ? (ushort)0x3F80 : (ushort)0;

  const int rA = wid, rB = 11 - wid, nA = 13 - rA;

  f32x4 acc[15];
  #pragma unroll
  for (int t = 0; t < 15; t++) acc[t] = (f32x4){0.f, 0.f, 0.f, 0.f};

  const float* xb = x + ((size_t)b * C192) * NSP;
  ushort* xg = xb16 + ((size_t)b * C192) * NSP;

  for (int ch = 0; ch < 2; ch++){
    __syncthreads();
    // stage 192x128 fp32 -> bf16 LDS (swizzled) + coalesced xb16 global write
    #pragma unroll 4
    for (int i = 0; i < 16; i++){
      int idx = i * 384 + tid;
      int r = idx >> 5, c4 = idx & 31;
      size_t gofs = (size_t)r * NSP + j0 + ch * 128 + c4 * 4;
      const float4 v = *(const float4*)(xb + gofs);
      uint2 u; u.x = f2bf2(v.x, v.y); u.y = f2bf2(v.z, v.w);
      int byte = r * 256 + c4 * 8; byte ^= (r & 7) << 4;
      *(uint2*)(lb + byte) = u;
      *(uint2*)(xg + gofs) = u;
    }
    __syncthreads();
    #pragma unroll
    for (int ks = 0; ks < 4; ks++){
      bf16x8 aA, aB;
      { int row = rA * 16 + l15; int byte = row * 256 + ks * 64 + hi * 16; byte ^= (l15 & 7) << 4;
        aA = *(const bf16x8*)(lb + byte); }
      { int row = rB * 16 + l15; int byte = row * 256 + ks * 64 + hi * 16; byte ^= (l15 & 7) << 4;
        aB = *(const bf16x8*)(lb + byte); }
      #pragma unroll
      for (int t = 0; t < 15; t++){
        int j = (t < nA) ? (rA + t) : (rB + t - nA);
        int row = j * 16 + l15; int byte = row * 256 + ks * 64 + hi * 16; byte ^= (l15 & 7) << 4;
        bf16x8 bf = *(const bf16x8*)(lb + byte);
        acc[t] = __builtin_amdgcn_mfma_f32_16x16x32_bf16((t < nA) ? aA : aB, bf, acc[t], 0, 0, 0);
      }
    }
  }
  // store compact bf16 partials
  ushort* gp = gpart + (size_t)(b * 256 + slice) * SLICE_ELEMS;
  #pragma unroll
  for (int t = 0; t < 15; t++){
    int i = (t < nA) ? rA : rB;
    int j = (t < nA) ? (rA + t) : (rB + t - nA);
    if (j < 12){
      int F = 12 * i - (i * (i - 1)) / 2 + (j - i);
      ushort* tp = gp + F * 256;
      #pragma unroll
      for (int r = 0; r < 4; r++) tp[(hi * 4 + r) * 16 + l15] = (ushort)f2bf1(acc[t][r]);
    } else if (l15 == 0){
      ushort* tp = gp + ONES_OFF_E + i * 16;
      #pragma unroll
      for (int r = 0; r < 4; r++) tp[hi * 4 + r] = (ushort)f2bf1(acc[t][r]);
    }
  }
}

// ---------------- K2: reduce compact partials -> G_aug [2][192][193] (mirrored); + WkT
__global__ __launch_bounds__(1024) void k_reduce(const ushort* __restrict__ gpart,
                                                 float* __restrict__ gaug,
                                                 const float* __restrict__ qkv_w,
                                                 float* __restrict__ wkT){
  int blk = blockIdx.x, tid = threadIdx.x;
  if (blk < 180){
    __shared__ float red[4][256];
    int b = blk / 90, slot = blk % 90;
    int q = tid >> 8, e = tid & 255;
    float sum = 0.f;
    if (slot < 78){
      const ushort* p = gpart + (size_t)(b * 256 + q) * SLICE_ELEMS + slot * 256 + e;
      #pragma unroll 8
      for (int k2 = 0; k2 < 64; k2++) sum += bf2f(p[(size_t)k2 * (4 * SLICE_ELEMS)]);
    } else if (e < 16){
      int i = slot - 78;
      const ushort* p = gpart + (size_t)(b * 256 + q) * SLICE_ELEMS + ONES_OFF_E + i * 16 + e;
      #pragma unroll 8
      for (int k2 = 0; k2 < 64; k2++) sum += bf2f(p[(size_t)k2 * (4 * SLICE_ELEMS)]);
    }
    red[q][e] = sum;
    __syncthreads();
    if (tid < 256){
      float tot = red[0][tid] + red[1][tid] + red[2][tid] + red[3][tid];
      if (slot < 78){
        int i = 0, off = 0;
        while (slot >= off + (12 - i)){ off += 12 - i; i++; }
        int j = i + (slot - off);
        int row = tid >> 4, col = tid & 15;
        int R = i * 16 + row, Cc = j * 16 + col;
        gaug[((size_t)b * C192 + R) * 193 + Cc] = tot;
        gaug[((size_t)b * C192 + Cc) * 193 + R] = tot;
      } else if (tid < 16){
        int i = slot - 78;
        gaug[((size_t)b * C192 + i * 16 + tid) * 193 + 192] = tot;
      }
    }
  } else {
    int idx = (blk - 180) * 1024 + tid;
    if (idx < 36864){
      int d = idx / 192, e = idx % 192;
      wkT[e * 192 + d] = qkv_w[(192 + d) * 192 + e];
    }
  }
}

// ---------------- T1: P_aug = Wq*G_aug, R_aug = Wk*G_aug; plus q/k norms
__global__ __launch_bounds__(256) void k_pr(const float* __restrict__ gaug,
                                            const float* __restrict__ qkv_w,
                                            const float* __restrict__ qkv_b,
                                            float* __restrict__ pr,
                                            float* __restrict__ norms){
  __shared__ float red[4];
  __shared__ float uSh;
  int blk = blockIdx.x, tid = threadIdx.x;
  int b = blk / 384, which = (blk / 192) % 2, c = blk % 192;
  const float* wrow = qkv_w + (which * 192 + c) * 192;
  float acc = 0.f;
  if (tid < 193){
    const float* g = gaug + (size_t)b * C192 * 193 + tid;
    #pragma unroll 4
    for (int e = 0; e < 192; e++) acc += wrow[e] * g[(size_t)e * 193];
    pr[(((size_t)b * 2 + which) * 192 + c) * 193 + tid] = acc;
  }
  if (tid == 192) uSh = acc;
  float v = (tid < 192) ? acc * wrow[tid] : 0.f;
  for (int o = 32; o > 0; o >>= 1) v += __shfl_down(v, o, 64);
  if ((tid & 63) == 0) red[tid >> 6] = v;
  __syncthreads();
  if (tid == 0){
    float s = red[0] + red[1] + red[2] + red[3];
    float bias = qkv_b[which * 192 + c];
    float n2 = s + 2.f * bias * uSh + 65536.f * bias * bias;
    norms[(b * 2 + which) * 192 + c] = fmaxf(sqrtf(fmaxf(n2, 0.f)), EPS_N);
  }
}

// ---------------- T3: S row -> scaled softmax -> attn [2][192][192]
__global__ __launch_bounds__(256) void k_attn(const float* __restrict__ pr,
                                              const float* __restrict__ wkT,
                                              const float* __restrict__ norms,
                                              const float* __restrict__ qkv_b,
                                              const float* __restrict__ temperature,
                                              float* __restrict__ attn){
  __shared__ float Pc[193];
  __shared__ float red[4];
  __shared__ float bcast;
  int blk = blockIdx.x, tid = threadIdx.x;
  int b = blk / 192, c = blk % 192;
  if (tid < 193) Pc[tid] = pr[(((size_t)b * 2 + 0) * 192 + c) * 193 + tid];
  __syncthreads();
  int d = tid;
  float logit = -1e30f, p = 0.f;
  if (d < 192){
    float sS = 0.f;
    #pragma unroll 4
    for (int e = 0; e < 192; e++) sS += Pc[e] * wkT[e * 192 + d];
    float bq = qkv_b[c], bk = qkv_b[192 + d];
    float w2 = pr[(((size_t)b * 2 + 1) * 192 + d) * 193 + 192];
    float Sv = sS + Pc[192] * bk + bq * w2 + 65536.f * bq * bk;
    float nq = norms[(b * 2 + 0) * 192 + c];
    float nk = norms[(b * 2 + 1) * 192 + d];
    logit = temperature[0] * Sv / (nq * nk);
  }
  float m = logit;
  for (int o = 32; o > 0; o >>= 1) m = fmaxf(m, __shfl_down(m, o, 64));
  if ((tid & 63) == 0) red[tid >> 6] = m;
  __syncthreads();
  if (tid == 0) bcast = fmaxf(fmaxf(red[0], red[1]), fmaxf(red[2], red[3]));
  __syncthreads();
  m = bcast;
  p = (d < 192) ? __expf(logit - m) : 0.f;
  float s = p;
  for (int o = 32; o > 0; o >>= 1) s += __shfl_down(s, o, 64);
  __syncthreads();
  if ((tid & 63) == 0) red[tid >> 6] = s;
  __syncthreads();
  if (tid == 0) bcast = red[0] + red[1] + red[2] + red[3];
  __syncthreads();
  if (d < 192) attn[((size_t)b * 192 + c) * 192 + d] = p / bcast;
}

// ---------------- T4: U_aug = attn @ [Wv | bv]   [2][192][193]
__global__ __launch_bounds__(256) void k_u(const float* __restrict__ attn,
                                           const float* __restrict__ qkv_w,
                                           const float* __restrict__ qkv_b,
                                           float* __restrict__ uaug){
  __shared__ float arow[192];
  int blk = blockIdx.x, tid = threadIdx.x;
  int b = blk / 192, c = blk % 192;
  if (tid < 192) arow[tid] = attn[((size_t)b * 192 + c) * 192 + tid];
  __syncthreads();
  int e = tid;
  if (e <= 192){
    float acc = 0.f;
    if (e < 192){
      #pragma unroll 4
      for (int d = 0; d < 192; d++) acc += arow[d] * qkv_w[(384 + d) * 192 + e];
    } else {
      #pragma unroll 4
      for (int d = 0; d < 192; d++) acc += arow[d] * qkv_b[384 + d];
    }
    uaug[((size_t)b * 192 + c) * 193 + e] = acc;
  }
}

// ---------------- T5: F = proj_w @ U (bf16), g = proj_w@h + proj_b
__global__ __launch_bounds__(256) void k_f(const float* __restrict__ uaug,
                                           const float* __restrict__ proj_w,
                                           const float* __restrict__ proj_b,
                                           ushort* __restrict__ fb,
                                           float* __restrict__ gvec){
  __shared__ float pw[192];
  int blk = blockIdx.x, tid = threadIdx.x;
  int b = blk / 192, f = blk % 192;
  if (tid < 192) pw[tid] = proj_w[f * 192 + tid];
  __syncthreads();
  int e = tid;
  if (e <= 192){
    float acc = 0.f;
    const float* u = uaug + (size_t)b * 192 * 193 + e;
    #pragma unroll 4
    for (int c2 = 0; c2 < 192; c2++) acc += pw[c2] * u[(size_t)c2 * 193];
    if (e < 192) fb[((size_t)b * 192 + f) * 192 + e] = (ushort)f2bf1(acc);
    else gvec[b * 192 + f] = acc + proj_b[f];
  }
}

// ---------------- K3: out = F @ x + g 1^T
// Stage x-chunk TRANSPOSED into LDS [sp:128][chan:192] via scalar ds_write_b16,
// dual-bit XOR swizzle g(sp) = (sp&7)^((sp>>3)&7) applied on write AND read.
// B-frags are then plain ds_read_b128 rows (the R1-verified k_gram pattern).
__global__ __launch_bounds__(256, 2) void k_out(const ushort* __restrict__ xb16,
                                                const ushort* __restrict__ fb,
                                                const float* __restrict__ gvec,
                                                float* __restrict__ out){
  __shared__ ushort xt[128 * 192];   // [sp][chan], row = 384 B
  char* lb = (char*)xt;
  const int tid = threadIdx.x;
  const int lane = tid & 63, wid = tid >> 6;
  const int l15 = lane & 15, hi = lane >> 4;
  const int b = blockIdx.x >> 9, cb = blockIdx.x & 511;
  const int j0 = cb * 128;

  // stage 192 chan x 128 sp, transposing in LDS
  const ushort* xg = xb16 + ((size_t)b * C192) * NSP + j0;
  #pragma unroll 2
  for (int i = 0; i < 12; i++){
    int idx = i * 256 + tid;
    int c = idx >> 4, s8 = idx & 15;
    int sp0 = s8 * 8;
    u32x4 v = *(const u32x4*)(xg + (size_t)c * NSP + sp0);
    uint vv[4] = {v.x, v.y, v.z, v.w};
    #pragma unroll
    for (int s = 0; s < 8; s++){
      int sp = sp0 + s;
      int byte = sp * 384 + c * 2;
      byte ^= (((sp & 7) ^ ((sp >> 3) & 7)) << 4);
      *(ushort*)(lb + byte) = (ushort)((vv[s >> 1] >> ((s & 1) * 16)) & 0xffff);
    }
  }

  float gfr[3][4];
  #pragma unroll
  for (int i = 0; i < 3; i++)
    #pragma unroll
    for (int r = 0; r < 4; r++)
      gfr[i][r] = gvec[b * 192 + (wid * 3 + i) * 16 + hi * 4 + r];

  f32x4 acc[3][8];
  #pragma unroll
  for (int i = 0; i < 3; i++)
    #pragma unroll
    for (int j = 0; j < 8; j++)
      acc[i][j] = (f32x4){0.f, 0.f, 0.f, 0.f};

  __syncthreads();

  for (int w = 0; w < 6; w++){
    bf16x8 aF[3];
    #pragma unroll
    for (int i = 0; i < 3; i++){
      const ushort* fr = fb + ((size_t)b * 192 + (wid * 3 + i) * 16 + l15) * 192;
      aF[i] = *(const bf16x8*)(fr + w * 32 + hi * 8);
    }
    #pragma unroll
    for (int ct = 0; ct < 8; ct++){
      int sp = ct * 16 + l15;
      int byte = sp * 384 + w * 64 + hi * 16;
      byte ^= (((sp & 7) ^ ((sp >> 3) & 7)) << 4);
      bf16x8 bf = *(const bf16x8*)(lb + byte);
      #pragma unroll
      for (int i = 0; i < 3; i++)
        acc[i][ct] = __builtin_amdgcn_mfma_f32_16x16x32_bf16(aF[i], bf, acc[i][ct], 0, 0, 0);
    }
  }

  #pragma unroll
  for (int i = 0; i < 3; i++){
    int row0 = (wid * 3 + i) * 16 + hi * 4;
    #pragma unroll
    for (int ct = 0; ct < 8; ct++){
      int sp = j0 + ct * 16 + l15;
      float* ob = out + ((size_t)b * C192 + row0) * NSP + sp;
      #pragma unroll
      for (int r = 0; r < 4; r++) ob[(size_t)r * NSP] = acc[i][ct][r] + gfr[i][r];
    }
  }
}

extern "C" void kernel_launch(void* const* d_in, const int* in_sizes, int n_in,
                              void* d_out, int out_size, void* d_ws, size_t ws_size,
                              hipStream_t stream){
  const float* x           = (const float*)d_in[0];
  const float* temperature = (const float*)d_in[1];
  const float* qkv_w       = (const float*)d_in[2];
  const float* qkv_b       = (const float*)d_in[3];
  const float* proj_w      = (const float*)d_in[4];
  const float* proj_b      = (const float*)d_in[5];
  float* out = (float*)d_out;
  char* ws = (char*)d_ws;

  ushort* gpart = (ushort*)(ws);                 // 512*20224*2    = 20,709,376
  ushort* xb16  = (ushort*)(ws + 20709376);      // 2*192*65536*2  = 50,331,648
  float*  gaug  = (float*) (ws + 71041024);      // 296,448
  float*  pr    = (float*) (ws + 71337472);      // 592,896
  float*  wkT   = (float*) (ws + 71930368);      // 147,456
  float*  norms = (float*) (ws + 72077824);      // 3,072
  float*  attn  = (float*) (ws + 72080896);      // 294,912
  float*  uaug  = (float*) (ws + 72375808);      // 296,448
  ushort* fb    = (ushort*)(ws + 72672256);      // 147,456
  float*  gvec  = (float*) (ws + 72819712);      // 1,536

  hipLaunchKernelGGL(k_gram,   dim3(512),  dim3(384),  0, stream, x, gpart, xb16);
  hipLaunchKernelGGL(k_reduce, dim3(216),  dim3(1024), 0, stream, gpart, gaug, qkv_w, wkT);
  hipLaunchKernelGGL(k_pr,     dim3(768),  dim3(256),  0, stream, gaug, qkv_w, qkv_b, pr, norms);
  hipLaunchKernelGGL(k_attn,   dim3(384),  dim3(256),  0, stream, pr, wkT, norms, qkv_b, temperature, attn);
  hipLaunchKernelGGL(k_u,      dim3(384),  dim3(256),  0, stream, attn, qkv_w, qkv_b, uaug);
  hipLaunchKernelGGL(k_f,      dim3(384),  dim3(256),  0, stream, uaug, proj_w, proj_b, fb, gvec);
  hipLaunchKernelGGL(k_out,    dim3(1024), dim3(256),  0, stream, xb16, fb, gvec, out);
}

// Round 4
// 167.927 us; speedup vs baseline: 1.2022x; 1.0816x over previous
//
#include <hip/hip_runtime.h>
#include <hip/hip_bf16.h>
#include <stdint.h>

typedef __attribute__((ext_vector_type(8))) __bf16 bf16x8;
typedef __attribute__((ext_vector_type(4))) float f32x4;
typedef __attribute__((ext_vector_type(4))) uint u32x4;

#define C192 192
#define NSP 65536
#define EPS_N 1e-12f

// per-slice compact partial layout (bf16): 78 full 16x16 tiles + 12 ones-col tiles(16)
#define SLICE_ELEMS 20224
#define ONES_OFF_E 19968   // 78*256

__device__ __forceinline__ uint32_t f2bf1(float a){
  uint32_t u = __float_as_uint(a);
  return (u + 0x7fffu + ((u >> 16) & 1u)) >> 16;
}
__device__ __forceinline__ uint32_t f2bf2(float lo, float hi){
  return f2bf1(lo) | (f2bf1(hi) << 16);
}
__device__ __forceinline__ float bf2f(ushort u){
  return __uint_as_float(((uint32_t)u) << 16);
}

// ---------------- K0: pure streaming fp32 -> bf16 convert (x -> xb16)
__global__ __launch_bounds__(256) void k_convert(const float* __restrict__ x,
                                                 ushort* __restrict__ xb16){
  const size_t total = (size_t)2 * C192 * NSP / 8;   // 3,145,728 units of 8 floats
  for (size_t idx = (size_t)blockIdx.x * 256 + threadIdx.x; idx < total;
       idx += (size_t)2048 * 256){
    const float4 v0 = *(const float4*)(x + idx * 8);
    const float4 v1 = *(const float4*)(x + idx * 8 + 4);
    uint4 u;
    u.x = f2bf2(v0.x, v0.y); u.y = f2bf2(v0.z, v0.w);
    u.z = f2bf2(v1.x, v1.y); u.w = f2bf2(v1.z, v1.w);
    *(uint4*)(xb16 + idx * 8) = u;
  }
}

// ---------------- K1: Gram upper-tri partials, 2-phase pipelined over 4 chunks of 64 cols
// grid 512: b = bid>>8, slice = bid&255 handles xb16[b][:, slice*256 .. +256)
// 6 waves; wave w owns row-tiles {w, 11-w}: 15 tiles (i,j) j>=i incl ones-col j=12
__global__ __launch_bounds__(384, 3) void k_gram(const ushort* __restrict__ xb16,
                                                 ushort* __restrict__ gpart){
  __shared__ ushort xs[2][208 * 64];   // 2 x 26624 B, 128 B rows, XOR-swizzled
  char* lb = (char*)&xs[0][0];
  const int tid = threadIdx.x;
  const int lane = tid & 63, wid = tid >> 6;
  const int l15 = lane & 15, hi = lane >> 4;
  const int b = blockIdx.x >> 8, slice = blockIdx.x & 255;
  const int j0 = slice * 256;

  // constant rows 192..207 in both buffers: row 192 = 1.0 bf16, rest 0
  for (int i = tid; i < 2048; i += 384){
    int buf = i >> 10, idx = i & 1023;
    int row = 192 + (idx >> 6), col = idx & 63;
    int byte = buf * 26624 + row * 128 + col * 2;
    byte ^= (row & 7) << 4;
    *(ushort*)(lb + byte) = (idx < 64) ? (ushort)0x3F80 : (ushort)0;
  }

  const int rA = wid, rB = 11 - wid, nA = 13 - rA;
  f32x4 acc[15];
  #pragma unroll
  for (int t = 0; t < 15; t++) acc[t] = (f32x4){0.f, 0.f, 0.f, 0.f};

  const ushort* xg = xb16 + ((size_t)b * C192) * NSP + j0;

  uint4 rg[4];
  auto LOADREGS = [&](int ch){
    #pragma unroll
    for (int q = 0; q < 4; q++){
      int k = wid * 4 + q;
      int row = k * 8 + (lane >> 3);
      int blk = (lane & 7) ^ (lane >> 3);     // pre-swizzled source block
      rg[q] = *(const uint4*)(xg + (size_t)row * NSP + ch * 64 + blk * 8);
    }
  };
  auto WRITE = [&](int bi){
    #pragma unroll
    for (int q = 0; q < 4; q++){
      int k = wid * 4 + q;
      *(uint4*)(lb + bi * 26624 + k * 1024 + lane * 16) = rg[q];
    }
  };
  auto COMPUTE = [&](int bi){
    const char* base = lb + bi * 26624;
    #pragma unroll
    for (int ks = 0; ks < 2; ks++){
      bf16x8 aA, aB;
      { int byte = (rA * 16 + l15) * 128 + ks * 64 + hi * 16; byte ^= (l15 & 7) << 4;
        aA = *(const bf16x8*)(base + byte); }
      { int byte = (rB * 16 + l15) * 128 + ks * 64 + hi * 16; byte ^= (l15 & 7) << 4;
        aB = *(const bf16x8*)(base + byte); }
      #pragma unroll
      for (int t = 0; t < 15; t++){
        int j = (t < nA) ? (rA + t) : (rB + t - nA);
        int byte = (j * 16 + l15) * 128 + ks * 64 + hi * 16; byte ^= (l15 & 7) << 4;
        bf16x8 bf = *(const bf16x8*)(base + byte);
        acc[t] = __builtin_amdgcn_mfma_f32_16x16x32_bf16((t < nA) ? aA : aB, bf, acc[t], 0, 0, 0);
      }
    }
  };

  LOADREGS(0); WRITE(0); __syncthreads();
  for (int ch = 0; ch < 4; ch++){
    if (ch < 3) LOADREGS(ch + 1);
    COMPUTE(ch & 1);
    if (ch < 3) WRITE((ch + 1) & 1);
    __syncthreads();
  }

  // store compact bf16 partials (layout identical to R3)
  ushort* gp = gpart + (size_t)(b * 256 + slice) * SLICE_ELEMS;
  #pragma unroll
  for (int t = 0; t < 15; t++){
    int i = (t < nA) ? rA : rB;
    int j = (t < nA) ? (rA + t) : (rB + t - nA);
    if (j < 12){
      int F = 12 * i - (i * (i - 1)) / 2 + (j - i);
      ushort* tp = gp + F * 256;
      #pragma unroll
      for (int r = 0; r < 4; r++) tp[(hi * 4 + r) * 16 + l15] = (ushort)f2bf1(acc[t][r]);
    } else if (l15 == 0){
      ushort* tp = gp + ONES_OFF_E + i * 16;
      #pragma unroll
      for (int r = 0; r < 4; r++) tp[hi * 4 + r] = (ushort)f2bf1(acc[t][r]);
    }
  }
}

// ---------------- K2: reduce compact partials -> G_aug [2][192][193] (mirrored); + WkT
__global__ __launch_bounds__(1024) void k_reduce(const ushort* __restrict__ gpart,
                                                 float* __restrict__ gaug,
                                                 const float* __restrict__ qkv_w,
                                                 float* __restrict__ wkT){
  int blk = blockIdx.x, tid = threadIdx.x;
  if (blk < 180){
    __shared__ float red[4][256];
    int b = blk / 90, slot = blk % 90;
    int q = tid >> 8, e = tid & 255;
    float sum = 0.f;
    if (slot < 78){
      const ushort* p = gpart + (size_t)(b * 256 + q) * SLICE_ELEMS + slot * 256 + e;
      #pragma unroll 8
      for (int k2 = 0; k2 < 64; k2++) sum += bf2f(p[(size_t)k2 * (4 * SLICE_ELEMS)]);
    } else if (e < 16){
      int i = slot - 78;
      const ushort* p = gpart + (size_t)(b * 256 + q) * SLICE_ELEMS + ONES_OFF_E + i * 16 + e;
      #pragma unroll 8
      for (int k2 = 0; k2 < 64; k2++) sum += bf2f(p[(size_t)k2 * (4 * SLICE_ELEMS)]);
    }
    red[q][e] = sum;
    __syncthreads();
    if (tid < 256){
      float tot = red[0][tid] + red[1][tid] + red[2][tid] + red[3][tid];
      if (slot < 78){
        int i = 0, off = 0;
        while (slot >= off + (12 - i)){ off += 12 - i; i++; }
        int j = i + (slot - off);
        int row = tid >> 4, col = tid & 15;
        int R = i * 16 + row, Cc = j * 16 + col;
        gaug[((size_t)b * C192 + R) * 193 + Cc] = tot;
        gaug[((size_t)b * C192 + Cc) * 193 + R] = tot;
      } else if (tid < 16){
        int i = slot - 78;
        gaug[((size_t)b * C192 + i * 16 + tid) * 193 + 192] = tot;
      }
    }
  } else {
    int idx = (blk - 180) * 1024 + tid;
    if (idx < 36864){
      int d = idx / 192, e = idx % 192;
      wkT[e * 192 + d] = qkv_w[(192 + d) * 192 + e];
    }
  }
}

// ---------------- T1: P_aug = Wq*G_aug, R_aug = Wk*G_aug; plus q/k norms
__global__ __launch_bounds__(256) void k_pr(const float* __restrict__ gaug,
                                            const float* __restrict__ qkv_w,
                                            const float* __restrict__ qkv_b,
                                            float* __restrict__ pr,
                                            float* __restrict__ norms){
  __shared__ float red[4];
  __shared__ float uSh;
  int blk = blockIdx.x, tid = threadIdx.x;
  int b = blk / 384, which = (blk / 192) % 2, c = blk % 192;
  const float* wrow = qkv_w + (which * 192 + c) * 192;
  float acc = 0.f;
  if (tid < 193){
    const float* g = gaug + (size_t)b * C192 * 193 + tid;
    #pragma unroll 4
    for (int e = 0; e < 192; e++) acc += wrow[e] * g[(size_t)e * 193];
    pr[(((size_t)b * 2 + which) * 192 + c) * 193 + tid] = acc;
  }
  if (tid == 192) uSh = acc;
  float v = (tid < 192) ? acc * wrow[tid] : 0.f;
  for (int o = 32; o > 0; o >>= 1) v += __shfl_down(v, o, 64);
  if ((tid & 63) == 0) red[tid >> 6] = v;
  __syncthreads();
  if (tid == 0){
    float s = red[0] + red[1] + red[2] + red[3];
    float bias = qkv_b[which * 192 + c];
    float n2 = s + 2.f * bias * uSh + 65536.f * bias * bias;
    norms[(b * 2 + which) * 192 + c] = fmaxf(sqrtf(fmaxf(n2, 0.f)), EPS_N);
  }
}

// ---------------- T3: S row -> scaled softmax -> attn [2][192][192]
__global__ __launch_bounds__(256) void k_attn(const float* __restrict__ pr,
                                              const float* __restrict__ wkT,
                                              const float* __restrict__ norms,
                                              const float* __restrict__ qkv_b,
                                              const float* __restrict__ temperature,
                                              float* __restrict__ attn){
  __shared__ float Pc[193];
  __shared__ float red[4];
  __shared__ float bcast;
  int blk = blockIdx.x, tid = threadIdx.x;
  int b = blk / 192, c = blk % 192;
  if (tid < 193) Pc[tid] = pr[(((size_t)b * 2 + 0) * 192 + c) * 193 + tid];
  __syncthreads();
  int d = tid;
  float logit = -1e30f, p = 0.f;
  if (d < 192){
    float sS = 0.f;
    #pragma unroll 4
    for (int e = 0; e < 192; e++) sS += Pc[e] * wkT[e * 192 + d];
    float bq = qkv_b[c], bk = qkv_b[192 + d];
    float w2 = pr[(((size_t)b * 2 + 1) * 192 + d) * 193 + 192];
    float Sv = sS + Pc[192] * bk + bq * w2 + 65536.f * bq * bk;
    float nq = norms[(b * 2 + 0) * 192 + c];
    float nk = norms[(b * 2 + 1) * 192 + d];
    logit = temperature[0] * Sv / (nq * nk);
  }
  float m = logit;
  for (int o = 32; o > 0; o >>= 1) m = fmaxf(m, __shfl_down(m, o, 64));
  if ((tid & 63) == 0) red[tid >> 6] = m;
  __syncthreads();
  if (tid == 0) bcast = fmaxf(fmaxf(red[0], red[1]), fmaxf(red[2], red[3]));
  __syncthreads();
  m = bcast;
  p = (d < 192) ? __expf(logit - m) : 0.f;
  float s = p;
  for (int o = 32; o > 0; o >>= 1) s += __shfl_down(s, o, 64);
  __syncthreads();
  if ((tid & 63) == 0) red[tid >> 6] = s;
  __syncthreads();
  if (tid == 0) bcast = red[0] + red[1] + red[2] + red[3];
  __syncthreads();
  if (d < 192) attn[((size_t)b * 192 + c) * 192 + d] = p / bcast;
}

// ---------------- T4: U_aug = attn @ [Wv | bv]   [2][192][193]
__global__ __launch_bounds__(256) void k_u(const float* __restrict__ attn,
                                           const float* __restrict__ qkv_w,
                                           const float* __restrict__ qkv_b,
                                           float* __restrict__ uaug){
  __shared__ float arow[192];
  int blk = blockIdx.x, tid = threadIdx.x;
  int b = blk / 192, c = blk % 192;
  if (tid < 192) arow[tid] = attn[((size_t)b * 192 + c) * 192 + tid];
  __syncthreads();
  int e = tid;
  if (e <= 192){
    float acc = 0.f;
    if (e < 192){
      #pragma unroll 4
      for (int d = 0; d < 192; d++) acc += arow[d] * qkv_w[(384 + d) * 192 + e];
    } else {
      #pragma unroll 4
      for (int d = 0; d < 192; d++) acc += arow[d] * qkv_b[384 + d];
    }
    uaug[((size_t)b * 192 + c) * 193 + e] = acc;
  }
}

// ---------------- T5: F = proj_w @ U (bf16), g = proj_w@h + proj_b
__global__ __launch_bounds__(256) void k_f(const float* __restrict__ uaug,
                                           const float* __restrict__ proj_w,
                                           const float* __restrict__ proj_b,
                                           ushort* __restrict__ fb,
                                           float* __restrict__ gvec){
  __shared__ float pw[192];
  int blk = blockIdx.x, tid = threadIdx.x;
  int b = blk / 192, f = blk % 192;
  if (tid < 192) pw[tid] = proj_w[f * 192 + tid];
  __syncthreads();
  int e = tid;
  if (e <= 192){
    float acc = 0.f;
    const float* u = uaug + (size_t)b * 192 * 193 + e;
    #pragma unroll 4
    for (int c2 = 0; c2 < 192; c2++) acc += pw[c2] * u[(size_t)c2 * 193];
    if (e < 192) fb[((size_t)b * 192 + f) * 192 + e] = (ushort)f2bf1(acc);
    else gvec[b * 192 + f] = acc + proj_b[f];
  }
}

// ---------------- K3: out = F @ x + g 1^T
// Stage x-chunk TRANSPOSED into LDS [sp:128][chan:192], channel-PAIRED ds_write_b32,
// dual-bit XOR swizzle g(sp) = (sp&7)^((sp>>3)&7) on write AND read (R3-verified).
__global__ __launch_bounds__(256, 3) void k_out(const ushort* __restrict__ xb16,
                                                const ushort* __restrict__ fb,
                                                const float* __restrict__ gvec,
                                                float* __restrict__ out){
  __shared__ ushort xt[128 * 192];   // [sp][chan], row = 384 B
  char* lb = (char*)xt;
  const int tid = threadIdx.x;
  const int lane = tid & 63, wid = tid >> 6;
  const int l15 = lane & 15, hi = lane >> 4;
  const int b = blockIdx.x >> 9, cb = blockIdx.x & 511;
  const int j0 = cb * 128;

  // stage 192 chan x 128 sp, transposing in LDS (channel pairs -> b32 writes)
  const ushort* xg = xb16 + ((size_t)b * C192) * NSP + j0;
  #pragma unroll 2
  for (int i = 0; i < 6; i++){
    int unit = i * 256 + tid;           // 0..1535
    int cp = unit >> 4, s8 = unit & 15;
    int c0 = cp * 2, sp0 = s8 * 8;
    u32x4 v0 = *(const u32x4*)(xg + (size_t)c0 * NSP + sp0);
    u32x4 v1 = *(const u32x4*)(xg + (size_t)(c0 + 1) * NSP + sp0);
    uint w0[4] = {v0.x, v0.y, v0.z, v0.w};
    uint w1[4] = {v1.x, v1.y, v1.z, v1.w};
    #pragma unroll
    for (int s = 0; s < 8; s++){
      int sp = sp0 + s;
      uint a = (w0[s >> 1] >> ((s & 1) * 16)) & 0xffffu;
      uint bb = (w1[s >> 1] >> ((s & 1) * 16)) & 0xffffu;
      int byte = sp * 384 + c0 * 2;
      byte ^= (((sp & 7) ^ ((sp >> 3) & 7)) << 4);
      *(uint*)(lb + byte) = a | (bb << 16);
    }
  }

  float gfr[3][4];
  #pragma unroll
  for (int i = 0; i < 3; i++)
    #pragma unroll
    for (int r = 0; r < 4; r++)
      gfr[i][r] = gvec[b * 192 + (wid * 3 + i) * 16 + hi * 4 + r];

  f32x4 acc[3][8];
  #pragma unroll
  for (int i = 0; i < 3; i++)
    #pragma unroll
    for (int j = 0; j < 8; j++)
      acc[i][j] = (f32x4){0.f, 0.f, 0.f, 0.f};

  __syncthreads();

  for (int w = 0; w < 6; w++){
    bf16x8 aF[3];
    #pragma unroll
    for (int i = 0; i < 3; i++){
      const ushort* fr = fb + ((size_t)b * 192 + (wid * 3 + i) * 16 + l15) * 192;
      aF[i] = *(const bf16x8*)(fr + w * 32 + hi * 8);
    }
    #pragma unroll
    for (int ct = 0; ct < 8; ct++){
      int sp = ct * 16 + l15;
      int byte = sp * 384 + w * 64 + hi * 16;
      byte ^= (((sp & 7) ^ ((sp >> 3) & 7)) << 4);
      bf16x8 bf = *(const bf16x8*)(lb + byte);
      #pragma unroll
      for (int i = 0; i < 3; i++)
        acc[i][ct] = __builtin_amdgcn_mfma_f32_16x16x32_bf16(aF[i], bf, acc[i][ct], 0, 0, 0);
    }
  }

  #pragma unroll
  for (int i = 0; i < 3; i++){
    int row0 = (wid * 3 + i) * 16 + hi * 4;
    #pragma unroll
    for (int ct = 0; ct < 8; ct++){
      int sp = j0 + ct * 16 + l15;
      float* ob = out + ((size_t)b * C192 + row0) * NSP + sp;
      #pragma unroll
      for (int r = 0; r < 4; r++) ob[(size_t)r * NSP] = acc[i][ct][r] + gfr[i][r];
    }
  }
}

extern "C" void kernel_launch(void* const* d_in, const int* in_sizes, int n_in,
                              void* d_out, int out_size, void* d_ws, size_t ws_size,
                              hipStream_t stream){
  const float* x           = (const float*)d_in[0];
  const float* temperature = (const float*)d_in[1];
  const float* qkv_w       = (const float*)d_in[2];
  const float* qkv_b       = (const float*)d_in[3];
  const float* proj_w      = (const float*)d_in[4];
  const float* proj_b      = (const float*)d_in[5];
  float* out = (float*)d_out;
  char* ws = (char*)d_ws;

  ushort* gpart = (ushort*)(ws);                 // 512*20224*2    = 20,709,376
  ushort* xb16  = (ushort*)(ws + 20709376);      // 2*192*65536*2  = 50,331,648
  float*  gaug  = (float*) (ws + 71041024);      // 296,448
  float*  pr    = (float*) (ws + 71337472);      // 592,896
  float*  wkT   = (float*) (ws + 71930368);      // 147,456
  float*  norms = (float*) (ws + 72077824);      // 3,072
  float*  attn  = (float*) (ws + 72080896);      // 294,912
  float*  uaug  = (float*) (ws + 72375808);      // 296,448
  ushort* fb    = (ushort*)(ws + 72672256);      // 147,456
  float*  gvec  = (float*) (ws + 72819712);      // 1,536

  hipLaunchKernelGGL(k_convert, dim3(2048), dim3(256),  0, stream, x, xb16);
  hipLaunchKernelGGL(k_gram,    dim3(512),  dim3(384),  0, stream, xb16, gpart);
  hipLaunchKernelGGL(k_reduce,  dim3(216),  dim3(1024), 0, stream, gpart, gaug, qkv_w, wkT);
  hipLaunchKernelGGL(k_pr,      dim3(768),  dim3(256),  0, stream, gaug, qkv_w, qkv_b, pr, norms);
  hipLaunchKernelGGL(k_attn,    dim3(384),  dim3(256),  0, stream, pr, wkT, norms, qkv_b, temperature, attn);
  hipLaunchKernelGGL(k_u,       dim3(384),  dim3(256),  0, stream, attn, qkv_w, qkv_b, uaug);
  hipLaunchKernelGGL(k_f,       dim3(384),  dim3(256),  0, stream, uaug, proj_w, proj_b, fb, gvec);
  hipLaunchKernelGGL(k_out,     dim3(1024), dim3(256),  0, stream, xb16, fb, gvec, out);
}

// Round 5
// 149.940 us; speedup vs baseline: 1.3464x; 1.1200x over previous
//
#include <hip/hip_runtime.h>
#include <hip/hip_bf16.h>
#include <stdint.h>

typedef __attribute__((ext_vector_type(8))) __bf16 bf16x8;
typedef __attribute__((ext_vector_type(4))) float f32x4;
typedef __attribute__((ext_vector_type(4))) uint u32x4;

#define C192 192
#define NSP 65536
#define EPS_N 1e-12f

// per-slice compact partial layout (bf16): 78 full 16x16 tiles + 12 ones-col tiles(16)
#define SLICE_ELEMS 20224
#define ONES_OFF_E 19968   // 78*256

__device__ __forceinline__ uint32_t f2bf1(float a){
  uint32_t u = __float_as_uint(a);
  return (u + 0x7fffu + ((u >> 16) & 1u)) >> 16;
}
__device__ __forceinline__ uint32_t f2bf2(float lo, float hi){
  return f2bf1(lo) | (f2bf1(hi) << 16);
}
__device__ __forceinline__ float bf2f(ushort u){
  return __uint_as_float(((uint32_t)u) << 16);
}

// ---------------- K1: Gram upper-tri partials, fused fp32->bf16 convert,
// 2-phase pipelined over 4 chunks of 64 cols.
// grid 512: b = bid>>8, slice = bid&255 handles x[b][:, slice*256 .. +256)
// 6 waves; wave w owns row-tiles {w, 11-w}: 15 tiles (i,j) j>=i incl ones-col j=12
__global__ __launch_bounds__(384, 3) void k_gram(const float* __restrict__ x,
                                                 ushort* __restrict__ gpart){
  __shared__ ushort xs[2][208 * 64];   // 2 x 26624 B, 128 B rows, XOR-swizzled
  char* lb = (char*)&xs[0][0];
  const int tid = threadIdx.x;
  const int lane = tid & 63, wid = tid >> 6;
  const int l15 = lane & 15, hi = lane >> 4;
  const int b = blockIdx.x >> 8, slice = blockIdx.x & 255;
  const int j0 = slice * 256;

  // constant rows 192..207 in both buffers: row 192 = 1.0 bf16, rest 0
  for (int i = tid; i < 2048; i += 384){
    int buf = i >> 10, idx = i & 1023;
    int row = 192 + (idx >> 6), col = idx & 63;
    int byte = buf * 26624 + row * 128 + col * 2;
    byte ^= (row & 7) << 4;
    *(ushort*)(lb + byte) = (idx < 64) ? (ushort)0x3F80 : (ushort)0;
  }

  const int rA = wid, rB = 11 - wid, nA = 13 - rA;
  f32x4 acc[15];
  #pragma unroll
  for (int t = 0; t < 15; t++) acc[t] = (f32x4){0.f, 0.f, 0.f, 0.f};

  const float* xg = x + ((size_t)b * C192) * NSP + j0;

  float4 rf[8];   // raw fp32 staging; convert happens in WRITE (after COMPUTE)
  auto LOADREGS = [&](int ch){
    #pragma unroll
    for (int q = 0; q < 4; q++){
      int k = wid * 4 + q;
      int row = k * 8 + (lane >> 3);
      int blk = (lane & 7) ^ (lane >> 3);     // pre-swizzled source block
      const float* src = xg + (size_t)row * NSP + ch * 64 + blk * 8;
      rf[2 * q]     = *(const float4*)(src);
      rf[2 * q + 1] = *(const float4*)(src + 4);
    }
  };
  auto WRITE = [&](int bi){
    #pragma unroll
    for (int q = 0; q < 4; q++){
      uint4 u;
      u.x = f2bf2(rf[2 * q].x,     rf[2 * q].y);
      u.y = f2bf2(rf[2 * q].z,     rf[2 * q].w);
      u.z = f2bf2(rf[2 * q + 1].x, rf[2 * q + 1].y);
      u.w = f2bf2(rf[2 * q + 1].z, rf[2 * q + 1].w);
      int k = wid * 4 + q;
      *(uint4*)(lb + bi * 26624 + k * 1024 + lane * 16) = u;
    }
  };
  auto COMPUTE = [&](int bi){
    const char* base = lb + bi * 26624;
    #pragma unroll
    for (int ks = 0; ks < 2; ks++){
      bf16x8 aA, aB;
      { int byte = (rA * 16 + l15) * 128 + ks * 64 + hi * 16; byte ^= (l15 & 7) << 4;
        aA = *(const bf16x8*)(base + byte); }
      { int byte = (rB * 16 + l15) * 128 + ks * 64 + hi * 16; byte ^= (l15 & 7) << 4;
        aB = *(const bf16x8*)(base + byte); }
      #pragma unroll
      for (int t = 0; t < 15; t++){
        int j = (t < nA) ? (rA + t) : (rB + t - nA);
        int byte = (j * 16 + l15) * 128 + ks * 64 + hi * 16; byte ^= (l15 & 7) << 4;
        bf16x8 bf = *(const bf16x8*)(base + byte);
        acc[t] = __builtin_amdgcn_mfma_f32_16x16x32_bf16((t < nA) ? aA : aB, bf, acc[t], 0, 0, 0);
      }
    }
  };

  LOADREGS(0); WRITE(0); __syncthreads();
  for (int ch = 0; ch < 4; ch++){
    if (ch < 3) LOADREGS(ch + 1);
    COMPUTE(ch & 1);
    if (ch < 3) WRITE((ch + 1) & 1);
    __syncthreads();
  }

  // store compact bf16 partials (layout identical to R3/R4)
  ushort* gp = gpart + (size_t)(b * 256 + slice) * SLICE_ELEMS;
  #pragma unroll
  for (int t = 0; t < 15; t++){
    int i = (t < nA) ? rA : rB;
    int j = (t < nA) ? (rA + t) : (rB + t - nA);
    if (j < 12){
      int F = 12 * i - (i * (i - 1)) / 2 + (j - i);
      ushort* tp = gp + F * 256;
      #pragma unroll
      for (int r = 0; r < 4; r++) tp[(hi * 4 + r) * 16 + l15] = (ushort)f2bf1(acc[t][r]);
    } else if (l15 == 0){
      ushort* tp = gp + ONES_OFF_E + i * 16;
      #pragma unroll
      for (int r = 0; r < 4; r++) tp[hi * 4 + r] = (ushort)f2bf1(acc[t][r]);
    }
  }
}

// ---------------- K2: reduce compact partials -> G_aug [2][192][193] (mirrored); + WkT
__global__ __launch_bounds__(1024) void k_reduce(const ushort* __restrict__ gpart,
                                                 float* __restrict__ gaug,
                                                 const float* __restrict__ qkv_w,
                                                 float* __restrict__ wkT){
  int blk = blockIdx.x, tid = threadIdx.x;
  if (blk < 180){
    __shared__ float red[4][256];
    int b = blk / 90, slot = blk % 90;
    int q = tid >> 8, e = tid & 255;
    float sum = 0.f;
    if (slot < 78){
      const ushort* p = gpart + (size_t)(b * 256 + q) * SLICE_ELEMS + slot * 256 + e;
      #pragma unroll 8
      for (int k2 = 0; k2 < 64; k2++) sum += bf2f(p[(size_t)k2 * (4 * SLICE_ELEMS)]);
    } else if (e < 16){
      int i = slot - 78;
      const ushort* p = gpart + (size_t)(b * 256 + q) * SLICE_ELEMS + ONES_OFF_E + i * 16 + e;
      #pragma unroll 8
      for (int k2 = 0; k2 < 64; k2++) sum += bf2f(p[(size_t)k2 * (4 * SLICE_ELEMS)]);
    }
    red[q][e] = sum;
    __syncthreads();
    if (tid < 256){
      float tot = red[0][tid] + red[1][tid] + red[2][tid] + red[3][tid];
      if (slot < 78){
        int i = 0, off = 0;
        while (slot >= off + (12 - i)){ off += 12 - i; i++; }
        int j = i + (slot - off);
        int row = tid >> 4, col = tid & 15;
        int R = i * 16 + row, Cc = j * 16 + col;
        gaug[((size_t)b * C192 + R) * 193 + Cc] = tot;
        gaug[((size_t)b * C192 + Cc) * 193 + R] = tot;
      } else if (tid < 16){
        int i = slot - 78;
        gaug[((size_t)b * C192 + i * 16 + tid) * 193 + 192] = tot;
      }
    }
  } else {
    int idx = (blk - 180) * 1024 + tid;
    if (idx < 36864){
      int d = idx / 192, e = idx % 192;
      wkT[e * 192 + d] = qkv_w[(192 + d) * 192 + e];
    }
  }
}

// ---------------- T1: P_aug = Wq*G_aug, R_aug = Wk*G_aug; plus q/k norms
__global__ __launch_bounds__(256) void k_pr(const float* __restrict__ gaug,
                                            const float* __restrict__ qkv_w,
                                            const float* __restrict__ qkv_b,
                                            float* __restrict__ pr,
                                            float* __restrict__ norms){
  __shared__ float red[4];
  __shared__ float uSh;
  int blk = blockIdx.x, tid = threadIdx.x;
  int b = blk / 384, which = (blk / 192) % 2, c = blk % 192;
  const float* wrow = qkv_w + (which * 192 + c) * 192;
  float acc = 0.f;
  if (tid < 193){
    const float* g = gaug + (size_t)b * C192 * 193 + tid;
    #pragma unroll 4
    for (int e = 0; e < 192; e++) acc += wrow[e] * g[(size_t)e * 193];
    pr[(((size_t)b * 2 + which) * 192 + c) * 193 + tid] = acc;
  }
  if (tid == 192) uSh = acc;
  float v = (tid < 192) ? acc * wrow[tid] : 0.f;
  for (int o = 32; o > 0; o >>= 1) v += __shfl_down(v, o, 64);
  if ((tid & 63) == 0) red[tid >> 6] = v;
  __syncthreads();
  if (tid == 0){
    float s = red[0] + red[1] + red[2] + red[3];
    float bias = qkv_b[which * 192 + c];
    float n2 = s + 2.f * bias * uSh + 65536.f * bias * bias;
    norms[(b * 2 + which) * 192 + c] = fmaxf(sqrtf(fmaxf(n2, 0.f)), EPS_N);
  }
}

// ---------------- T3: S row -> scaled softmax -> attn [2][192][192]
__global__ __launch_bounds__(256) void k_attn(const float* __restrict__ pr,
                                              const float* __restrict__ wkT,
                                              const float* __restrict__ norms,
                                              const float* __restrict__ qkv_b,
                                              const float* __restrict__ temperature,
                                              float* __restrict__ attn){
  __shared__ float Pc[193];
  __shared__ float red[4];
  __shared__ float bcast;
  int blk = blockIdx.x, tid = threadIdx.x;
  int b = blk / 192, c = blk % 192;
  if (tid < 193) Pc[tid] = pr[(((size_t)b * 2 + 0) * 192 + c) * 193 + tid];
  __syncthreads();
  int d = tid;
  float logit = -1e30f, p = 0.f;
  if (d < 192){
    float sS = 0.f;
    #pragma unroll 4
    for (int e = 0; e < 192; e++) sS += Pc[e] * wkT[e * 192 + d];
    float bq = qkv_b[c], bk = qkv_b[192 + d];
    float w2 = pr[(((size_t)b * 2 + 1) * 192 + d) * 193 + 192];
    float Sv = sS + Pc[192] * bk + bq * w2 + 65536.f * bq * bk;
    float nq = norms[(b * 2 + 0) * 192 + c];
    float nk = norms[(b * 2 + 1) * 192 + d];
    logit = temperature[0] * Sv / (nq * nk);
  }
  float m = logit;
  for (int o = 32; o > 0; o >>= 1) m = fmaxf(m, __shfl_down(m, o, 64));
  if ((tid & 63) == 0) red[tid >> 6] = m;
  __syncthreads();
  if (tid == 0) bcast = fmaxf(fmaxf(red[0], red[1]), fmaxf(red[2], red[3]));
  __syncthreads();
  m = bcast;
  p = (d < 192) ? __expf(logit - m) : 0.f;
  float s = p;
  for (int o = 32; o > 0; o >>= 1) s += __shfl_down(s, o, 64);
  __syncthreads();
  if ((tid & 63) == 0) red[tid >> 6] = s;
  __syncthreads();
  if (tid == 0) bcast = red[0] + red[1] + red[2] + red[3];
  __syncthreads();
  if (d < 192) attn[((size_t)b * 192 + c) * 192 + d] = p / bcast;
}

// ---------------- T4: U_aug = attn @ [Wv | bv]   [2][192][193]
__global__ __launch_bounds__(256) void k_u(const float* __restrict__ attn,
                                           const float* __restrict__ qkv_w,
                                           const float* __restrict__ qkv_b,
                                           float* __restrict__ uaug){
  __shared__ float arow[192];
  int blk = blockIdx.x, tid = threadIdx.x;
  int b = blk / 192, c = blk % 192;
  if (tid < 192) arow[tid] = attn[((size_t)b * 192 + c) * 192 + tid];
  __syncthreads();
  int e = tid;
  if (e <= 192){
    float acc = 0.f;
    if (e < 192){
      #pragma unroll 4
      for (int d = 0; d < 192; d++) acc += arow[d] * qkv_w[(384 + d) * 192 + e];
    } else {
      #pragma unroll 4
      for (int d = 0; d < 192; d++) acc += arow[d] * qkv_b[384 + d];
    }
    uaug[((size_t)b * 192 + c) * 193 + e] = acc;
  }
}

// ---------------- T5: F = proj_w @ U (bf16), g = proj_w@h + proj_b
__global__ __launch_bounds__(256) void k_f(const float* __restrict__ uaug,
                                           const float* __restrict__ proj_w,
                                           const float* __restrict__ proj_b,
                                           ushort* __restrict__ fb,
                                           float* __restrict__ gvec){
  __shared__ float pw[192];
  int blk = blockIdx.x, tid = threadIdx.x;
  int b = blk / 192, f = blk % 192;
  if (tid < 192) pw[tid] = proj_w[f * 192 + tid];
  __syncthreads();
  int e = tid;
  if (e <= 192){
    float acc = 0.f;
    const float* u = uaug + (size_t)b * 192 * 193 + e;
    #pragma unroll 4
    for (int c2 = 0; c2 < 192; c2++) acc += pw[c2] * u[(size_t)c2 * 193];
    if (e < 192) fb[((size_t)b * 192 + f) * 192 + e] = (ushort)f2bf1(acc);
    else gvec[b * 192 + f] = acc + proj_b[f];
  }
}

// ---------------- K3: out = F @ x + g 1^T  (reads fp32 x directly, converts in staging)
// Stage x-chunk TRANSPOSED into LDS [sp:128][chan:192], channel-PAIRED ds_write_b32,
// dual-bit XOR swizzle g(sp) = (sp&7)^((sp>>3)&7) on write AND read (R3-verified).
__global__ __launch_bounds__(256, 3) void k_out(const float* __restrict__ x,
                                                const ushort* __restrict__ fb,
                                                const float* __restrict__ gvec,
                                                float* __restrict__ out){
  __shared__ ushort xt[128 * 192];   // [sp][chan], row = 384 B
  char* lb = (char*)xt;
  const int tid = threadIdx.x;
  const int lane = tid & 63, wid = tid >> 6;
  const int l15 = lane & 15, hi = lane >> 4;
  const int b = blockIdx.x >> 9, cb = blockIdx.x & 511;
  const int j0 = cb * 128;

  // stage 192 chan x 128 sp, transposing in LDS (channel pairs -> b32 writes)
  const float* xg = x + ((size_t)b * C192) * NSP + j0;
  #pragma unroll 2
  for (int i = 0; i < 6; i++){
    int unit = i * 256 + tid;           // 0..1535
    int cp = unit >> 4, s8 = unit & 15;
    int c0 = cp * 2, sp0 = s8 * 8;
    const float* r0 = xg + (size_t)c0 * NSP + sp0;
    const float* r1 = xg + (size_t)(c0 + 1) * NSP + sp0;
    float4 a0 = *(const float4*)(r0);
    float4 a1 = *(const float4*)(r0 + 4);
    float4 b0 = *(const float4*)(r1);
    float4 b1 = *(const float4*)(r1 + 4);
    float fa[8] = {a0.x, a0.y, a0.z, a0.w, a1.x, a1.y, a1.z, a1.w};
    float fc[8] = {b0.x, b0.y, b0.z, b0.w, b1.x, b1.y, b1.z, b1.w};
    #pragma unroll
    for (int s = 0; s < 8; s++){
      int sp = sp0 + s;
      int byte = sp * 384 + c0 * 2;
      byte ^= (((sp & 7) ^ ((sp >> 3) & 7)) << 4);
      *(uint*)(lb + byte) = f2bf2(fa[s], fc[s]);
    }
  }

  float gfr[3][4];
  #pragma unroll
  for (int i = 0; i < 3; i++)
    #pragma unroll
    for (int r = 0; r < 4; r++)
      gfr[i][r] = gvec[b * 192 + (wid * 3 + i) * 16 + hi * 4 + r];

  f32x4 acc[3][8];
  #pragma unroll
  for (int i = 0; i < 3; i++)
    #pragma unroll
    for (int j = 0; j < 8; j++)
      acc[i][j] = (f32x4){0.f, 0.f, 0.f, 0.f};

  __syncthreads();

  for (int w = 0; w < 6; w++){
    bf16x8 aF[3];
    #pragma unroll
    for (int i = 0; i < 3; i++){
      const ushort* fr = fb + ((size_t)b * 192 + (wid * 3 + i) * 16 + l15) * 192;
      aF[i] = *(const bf16x8*)(fr + w * 32 + hi * 8);
    }
    #pragma unroll
    for (int ct = 0; ct < 8; ct++){
      int sp = ct * 16 + l15;
      int byte = sp * 384 + w * 64 + hi * 16;
      byte ^= (((sp & 7) ^ ((sp >> 3) & 7)) << 4);
      bf16x8 bf = *(const bf16x8*)(lb + byte);
      #pragma unroll
      for (int i = 0; i < 3; i++)
        acc[i][ct] = __builtin_amdgcn_mfma_f32_16x16x32_bf16(aF[i], bf, acc[i][ct], 0, 0, 0);
    }
  }

  #pragma unroll
  for (int i = 0; i < 3; i++){
    int row0 = (wid * 3 + i) * 16 + hi * 4;
    #pragma unroll
    for (int ct = 0; ct < 8; ct++){
      int sp = j0 + ct * 16 + l15;
      float* ob = out + ((size_t)b * C192 + row0) * NSP + sp;
      #pragma unroll
      for (int r = 0; r < 4; r++) ob[(size_t)r * NSP] = acc[i][ct][r] + gfr[i][r];
    }
  }
}

extern "C" void kernel_launch(void* const* d_in, const int* in_sizes, int n_in,
                              void* d_out, int out_size, void* d_ws, size_t ws_size,
                              hipStream_t stream){
  const float* x           = (const float*)d_in[0];
  const float* temperature = (const float*)d_in[1];
  const float* qkv_w       = (const float*)d_in[2];
  const float* qkv_b       = (const float*)d_in[3];
  const float* proj_w      = (const float*)d_in[4];
  const float* proj_b      = (const float*)d_in[5];
  float* out = (float*)d_out;
  char* ws = (char*)d_ws;

  ushort* gpart = (ushort*)(ws);                 // 512*20224*2 = 20,709,376
  float*  gaug  = (float*) (ws + 20709376);      // 296,448
  float*  pr    = (float*) (ws + 21005824);      // 592,896
  float*  wkT   = (float*) (ws + 21598720);      // 147,456
  float*  norms = (float*) (ws + 21746176);      // 3,072
  float*  attn  = (float*) (ws + 21749248);      // 294,912
  float*  uaug  = (float*) (ws + 22044160);      // 296,448
  ushort* fb    = (ushort*)(ws + 22340608);      // 147,456
  float*  gvec  = (float*) (ws + 22488064);      // 1,536

  hipLaunchKernelGGL(k_gram,   dim3(512),  dim3(384),  0, stream, x, gpart);
  hipLaunchKernelGGL(k_reduce, dim3(216),  dim3(1024), 0, stream, gpart, gaug, qkv_w, wkT);
  hipLaunchKernelGGL(k_pr,     dim3(768),  dim3(256),  0, stream, gaug, qkv_w, qkv_b, pr, norms);
  hipLaunchKernelGGL(k_attn,   dim3(384),  dim3(256),  0, stream, pr, wkT, norms, qkv_b, temperature, attn);
  hipLaunchKernelGGL(k_u,      dim3(384),  dim3(256),  0, stream, attn, qkv_w, qkv_b, uaug);
  hipLaunchKernelGGL(k_f,      dim3(384),  dim3(256),  0, stream, uaug, proj_w, proj_b, fb, gvec);
  hipLaunchKernelGGL(k_out,    dim3(1024), dim3(256),  0, stream, x, fb, gvec, out);
}